// Round 10
// baseline (244.986 us; speedup 1.0000x reference)
//
#include <hip/hip_runtime.h>

#define E_DIM 69120
#define N1 60
#define H 32
#define CC 3
#define TE1 64
#define NB1 (E_DIM / TE1)   // 1080 chain blocks
#define CHK 128
#define NBP (E_DIM / CHK)   // 540 reduce blocks
#define SDS 68              // d-tile stride
#define SBA 36              // chain buffer stride
#define PSZ (N1 * H)        // 1920
#define TE0 256
#define NB0 (E_DIM / TE0)   // 270 (fallback)

__device__ __forceinline__ float relu_dot4(const float4 d, const float w, const float4 t) {
    return fmaxf(fmaf(d.x, w, t.x), 0.f) + fmaxf(fmaf(d.y, w, t.y), 0.f)
         + fmaxf(fmaf(d.z, w, t.z), 0.f) + fmaxf(fmaf(d.w, w, t.w), 0.f);
}

// =====================================================================
// kP1: chain A: t1 -> vb -> vw, write vwT[h][e] (b_fu folded).
// 256 thr: (eL 0..63, hg 0..3 -> 8 h). LDS 25.5 KB -> 6 blocks/CU.
// =====================================================================
__global__ __launch_bounds__(256, 6) void kP1(
    const float* __restrict__ d,
    const float* __restrict__ Wfvb, const float* __restrict__ bfvb,
    const float* __restrict__ Wgvb, const float* __restrict__ bgvb,
    const float* __restrict__ Wfu,  const float* __restrict__ bfu,
    float* __restrict__ vwT)
{
    __shared__ __align__(16) float ds[N1 * SDS];
    __shared__ __align__(16) float bufA[64 * SBA];
    const int tid = threadIdx.x;
    const long sE = (long)blockIdx.x * TE1;

    for (int i = tid; i < N1 * (TE1 / 4); i += 256) {
        const int n = i >> 4, c = (i & 15) * 4;
        *(float4*)(ds + n * SDS + c) = *(const float4*)(d + (long)n * E_DIM + sE + c);
    }
    __syncthreads();

    const int eL = tid & 63;
    const int h0 = __builtin_amdgcn_readfirstlane((threadIdx.x >> 6) * 8);

    // ph1: t1 = mean_n relu(d*wf+bf)  (1/N1 folded; dual accumulators)
    {
        float wf[8], bf[8], ta[8], tb[8];
        #pragma unroll
        for (int j = 0; j < 8; ++j) {
            wf[j] = Wfvb[h0 + j] * (1.f / N1);
            bf[j] = bfvb[h0 + j] * (1.f / N1);
            ta[j] = 0.f; tb[j] = 0.f;
        }
        const float* dp = ds + eL;
        #pragma unroll 5
        for (int n = 0; n < N1; n += 2) {
            const float dv0 = dp[n * SDS];
            const float dv1 = dp[(n + 1) * SDS];
            #pragma unroll
            for (int j = 0; j < 8; ++j) {
                ta[j] += fmaxf(fmaf(dv0, wf[j], bf[j]), 0.f);
                tb[j] += fmaxf(fmaf(dv1, wf[j], bf[j]), 0.f);
            }
        }
        *(float4*)(bufA + eL * SBA + h0)     = make_float4(ta[0]+tb[0], ta[1]+tb[1], ta[2]+tb[2], ta[3]+tb[3]);
        *(float4*)(bufA + eL * SBA + h0 + 4) = make_float4(ta[4]+tb[4], ta[5]+tb[5], ta[6]+tb[6], ta[7]+tb[7]);
    }
    __syncthreads();

    float row[32];

    // mv1: vb = relu(t1 @ Wgvb + bgvb), in-place (read row, sync, write)
    #pragma unroll
    for (int q = 0; q < 8; ++q)
        *(float4*)(row + q * 4) = *(const float4*)(bufA + eL * SBA + q * 4);
    __syncthreads();
    {
        float acc[8];
        #pragma unroll
        for (int j = 0; j < 8; ++j) acc[j] = bgvb[h0 + j];
        #pragma unroll
        for (int k = 0; k < H; ++k) {
            const float t = row[k];
            #pragma unroll
            for (int j = 0; j < 8; ++j) acc[j] = fmaf(t, Wgvb[k * H + h0 + j], acc[j]);
        }
        #pragma unroll
        for (int j = 0; j < 8; ++j) acc[j] = fmaxf(acc[j], 0.f);
        *(float4*)(bufA + eL * SBA + h0)     = make_float4(acc[0], acc[1], acc[2], acc[3]);
        *(float4*)(bufA + eL * SBA + h0 + 4) = make_float4(acc[4], acc[5], acc[6], acc[7]);
    }
    __syncthreads();

    // mv2: vw = vb @ Wu_v + b_fu -> global vwT (transposed, coalesced)
    #pragma unroll
    for (int q = 0; q < 8; ++q)
        *(float4*)(row + q * 4) = *(const float4*)(bufA + eL * SBA + q * 4);
    {
        float acc[8];
        #pragma unroll
        for (int j = 0; j < 8; ++j) acc[j] = bfu[h0 + j];
        #pragma unroll
        for (int k = 0; k < H; ++k) {
            const float t = row[k];
            #pragma unroll
            for (int j = 0; j < 8; ++j) acc[j] = fmaf(t, Wfu[k * H + h0 + j], acc[j]);
        }
        #pragma unroll
        for (int j = 0; j < 8; ++j) vwT[(long)(h0 + j) * E_DIM + sE + eL] = acc[j];
    }
}

// =====================================================================
// kP4: chain C: m -> v -> vz, write vzT (b_fz folded). uwb PRE-SCALED
// by 1/N1 (kB does it); read as wave-uniform scalar loads.
// =====================================================================
__global__ __launch_bounds__(256, 6) void kP4(
    const float* __restrict__ d, const float* __restrict__ uwb,
    const float* __restrict__ Wfvc,
    const float* __restrict__ Wgvc, const float* __restrict__ bgvc,
    const float* __restrict__ Wfz,  const float* __restrict__ bfz,
    float* __restrict__ vzT)
{
    __shared__ __align__(16) float ds[N1 * SDS];
    __shared__ __align__(16) float bufA[64 * SBA];
    const int tid = threadIdx.x;
    const long sE = (long)blockIdx.x * TE1;

    for (int i = tid; i < N1 * (TE1 / 4); i += 256) {
        const int n = i >> 4, c = (i & 15) * 4;
        *(float4*)(ds + n * SDS + c) = *(const float4*)(d + (long)n * E_DIM + sE + c);
    }
    __syncthreads();

    const int eL = tid & 63;
    const int h0 = __builtin_amdgcn_readfirstlane((threadIdx.x >> 6) * 8);

    // ph1: m = mean_n relu(d*wvd + u_n); wvd scaled, u pre-scaled
    {
        float wvd[8], ma[8], mb[8];
        #pragma unroll
        for (int j = 0; j < 8; ++j) { wvd[j] = Wfvc[H * H + h0 + j] * (1.f / N1); ma[j] = 0.f; mb[j] = 0.f; }
        const float* dp = ds + eL;
        #pragma unroll 5
        for (int n = 0; n < N1; n += 2) {
            const float dv0 = dp[n * SDS];
            const float dv1 = dp[(n + 1) * SDS];
            const float* u0 = uwb + n * H + h0;          // wave-uniform -> s_load
            const float* u1 = uwb + (n + 1) * H + h0;
            #pragma unroll
            for (int j = 0; j < 8; ++j) {
                ma[j] += fmaxf(fmaf(dv0, wvd[j], u0[j]), 0.f);
                mb[j] += fmaxf(fmaf(dv1, wvd[j], u1[j]), 0.f);
            }
        }
        *(float4*)(bufA + eL * SBA + h0)     = make_float4(ma[0]+mb[0], ma[1]+mb[1], ma[2]+mb[2], ma[3]+mb[3]);
        *(float4*)(bufA + eL * SBA + h0 + 4) = make_float4(ma[4]+mb[4], ma[5]+mb[5], ma[6]+mb[6], ma[7]+mb[7]);
    }
    __syncthreads();

    float row[32];

    // mv1: v = relu(m @ Wgvc + bgvc), in-place
    #pragma unroll
    for (int q = 0; q < 8; ++q)
        *(float4*)(row + q * 4) = *(const float4*)(bufA + eL * SBA + q * 4);
    __syncthreads();
    {
        float acc[8];
        #pragma unroll
        for (int j = 0; j < 8; ++j) acc[j] = bgvc[h0 + j];
        #pragma unroll
        for (int k = 0; k < H; ++k) {
            const float t = row[k];
            #pragma unroll
            for (int j = 0; j < 8; ++j) acc[j] = fmaf(t, Wgvc[k * H + h0 + j], acc[j]);
        }
        #pragma unroll
        for (int j = 0; j < 8; ++j) acc[j] = fmaxf(acc[j], 0.f);
        *(float4*)(bufA + eL * SBA + h0)     = make_float4(acc[0], acc[1], acc[2], acc[3]);
        *(float4*)(bufA + eL * SBA + h0 + 4) = make_float4(acc[4], acc[5], acc[6], acc[7]);
    }
    __syncthreads();

    // mv2: vz = v @ Wz_v + b_fz -> global vzT
    #pragma unroll
    for (int q = 0; q < 8; ++q)
        *(float4*)(row + q * 4) = *(const float4*)(bufA + eL * SBA + q * 4);
    {
        float acc[8];
        #pragma unroll
        for (int j = 0; j < 8; ++j) acc[j] = bfz[h0 + j];
        #pragma unroll
        for (int k = 0; k < H; ++k) {
            const float t = row[k];
            #pragma unroll
            for (int j = 0; j < 8; ++j) acc[j] = fmaf(t, Wfz[k * H + h0 + j], acc[j]);
        }
        #pragma unroll
        for (int j = 0; j < 8; ++j) vzT[(long)(h0 + j) * E_DIM + sE + eL] = acc[j];
    }
}

// =====================================================================
// kP2 (also P5): streaming reduction. No LDS, no barriers.
// 512 thr = (n 0..63, hg 0..7 -> 4 h); chunk = 128 e.
// part[blk][n*H+h] = sum_e relu(d[n,e]*wud[h] + wT[h,e])
// =====================================================================
__global__ __launch_bounds__(512, 4) void kP2(
    const float* __restrict__ dmat, const float* __restrict__ wT,
    const float* __restrict__ Wf,
    float* __restrict__ part)
{
    const int tid = threadIdx.x;
    const int n = tid >> 3, hg = tid & 7, h0 = hg * 4;
    if (n >= N1) return;
    const long sE = (long)blockIdx.x * CHK;

    float wud[4], acc[4];
    #pragma unroll
    for (int j = 0; j < 4; ++j) { wud[j] = Wf[H * H + h0 + j]; acc[j] = 0.f; }

    const float* dr = dmat + (long)n * E_DIM + sE;
    #pragma unroll 2
    for (int e = 0; e < CHK; e += 8) {
        const float4 dA = *(const float4*)(dr + e);
        const float4 dB = *(const float4*)(dr + e + 4);
        #pragma unroll
        for (int j = 0; j < 4; ++j) {
            const float* wp = wT + (long)(h0 + j) * E_DIM + sE + e;
            const float4 wA = *(const float4*)(wp);
            const float4 wB = *(const float4*)(wp + 4);
            acc[j] += relu_dot4(dA, wud[j], wA) + relu_dot4(dB, wud[j], wB);
        }
    }
    *(float4*)(part + (long)blockIdx.x * PSZ + n * H + h0) =
        make_float4(acc[0], acc[1], acc[2], acc[3]);
}

// reduce part[NBP][PSZ] -> out[PSZ]; grid = PSZ/16 = 120 blocks
__global__ __launch_bounds__(256) void kR(
    const float* __restrict__ part, float* __restrict__ out)
{
    __shared__ float red[16][17];
    const int tid = threadIdx.x;
    const int oLoc = tid & 15, c = tid >> 4;
    const int o = blockIdx.x * 16 + oLoc;
    const int b0 = c * 34;
    const int bN = (NBP - b0 < 34) ? (NBP - b0) : 34;
    const float* p = part + (long)b0 * PSZ + o;
    float s = 0.f;
    #pragma unroll 2
    for (int b = 0; b < bN; ++b) s += p[(long)b * PSZ];
    red[c][oLoc] = s;
    __syncthreads();
    if (tid < 16) {
        float t = 0.f;
        #pragma unroll
        for (int ci = 0; ci < 16; ++ci) t += red[ci][tid];
        out[blockIdx.x * 16 + tid] = t;
    }
}

// kB: tiny chain; uwb written with uscale factor (1/N1 for main path)
__global__ __launch_bounds__(1024) void kB(
    const float* __restrict__ alphaAcc, const int* __restrict__ label,
    const float* __restrict__ Wfvb, const float* __restrict__ bfvb,
    const float* __restrict__ Wgvb, const float* __restrict__ bgvb,
    const float* __restrict__ Wfu,  const float* __restrict__ bfu,
    const float* __restrict__ Wgu,  const float* __restrict__ bgu,
    const float* __restrict__ Wfvc, const float* __restrict__ bfvc,
    float uscale, float* __restrict__ uwb)
{
    __shared__ float up_l[N1 * H];
    __shared__ float un_l[N1 * H];
    __shared__ float cb_l[CC * H];
    __shared__ float cw_l[CC * H];
    __shared__ int   cnt[CC];
    const int tid = threadIdx.x;

    if (tid < CC) cnt[tid] = 0;
    __syncthreads();
    if (tid < N1) atomicAdd(&cnt[label[tid]], 1);
    __syncthreads();

    if (tid < CC * H) {
        const int c = tid / H, h = tid % H;
        const float nc = (float)cnt[c];
        float s = bgvb[h];
        #pragma unroll
        for (int k = 0; k < H; ++k) {
            const float t1c = (nc * fmaxf(Wfvb[k] + bfvb[k], 0.f) +
                               ((float)N1 - nc) * fmaxf(bfvb[k], 0.f)) * (1.f / N1);
            s = fmaf(t1c, Wgvb[k * H + h], s);
        }
        cb_l[tid] = fmaxf(s, 0.f);
    }
    __syncthreads();
    if (tid < CC * H) {
        const int c = tid / H, h = tid % H;
        float s = bfu[h];
        #pragma unroll
        for (int k = 0; k < H; ++k) s = fmaf(cb_l[c * H + k], Wfu[k * H + h], s);
        cw_l[tid] = s;
    }
    __syncthreads();
    for (int t = tid; t < N1 * H; t += 1024) {
        const int n = t >> 5, h = t & 31;
        const int ln = label[n];
        const float wud = Wfu[H * H + h];
        float s = 0.f;
        #pragma unroll
        for (int c = 0; c < CC; ++c)
            s += fmaxf(cw_l[c * H + h] + ((c == ln) ? wud : 0.f), 0.f);
        up_l[t] = alphaAcc[t] * (1.f / E_DIM) + s * (1.f / CC);
    }
    __syncthreads();
    for (int t = tid; t < N1 * H; t += 1024) {
        const int n = t >> 5, h = t & 31;
        float s = bgu[h];
        #pragma unroll
        for (int k = 0; k < H; ++k) s = fmaf(up_l[n * H + k], Wgu[k * H + h], s);
        un_l[t] = fmaxf(s, 0.f);
    }
    __syncthreads();
    for (int t = tid; t < N1 * H; t += 1024) {
        const int n = t >> 5, h = t & 31;
        float s = bfvc[h];
        #pragma unroll
        for (int k = 0; k < H; ++k) s = fmaf(un_l[n * H + k], Wfvc[k * H + h], s);
        uwb[t] = s * uscale;
    }
}

__global__ __launch_bounds__(1024) void kD(
    const float* __restrict__ zAcc,
    const float* __restrict__ Wgz, const float* __restrict__ bgz,
    float* __restrict__ out)
{
    __shared__ float z_l[N1 * H];
    const int tid = threadIdx.x;
    for (int t = tid; t < N1 * H; t += 1024) z_l[t] = zAcc[t] * (1.f / E_DIM);
    __syncthreads();
    for (int t = tid; t < N1 * H; t += 1024) {
        const int n = t >> 5, h = t & 31;
        float s = bgz[h];
        #pragma unroll
        for (int k = 0; k < H; ++k) s = fmaf(z_l[n * H + k], Wgz[k * H + h], s);
        out[t] = fmaxf(s, 0.f);
    }
}

// ===================== fallback (r2-proven, tiny ws) ==================
__global__ __launch_bounds__(256) void kA0(
    const float* __restrict__ d,
    const float* __restrict__ Wfvb, const float* __restrict__ bfvb,
    const float* __restrict__ Wgvb, const float* __restrict__ bgvb,
    const float* __restrict__ Wfu,  const float* __restrict__ bfu,
    float* __restrict__ alphaAcc)
{
    __shared__ float vw_l[TE0][H + 1];
    const int tid = threadIdx.x;
    const long e0 = (long)blockIdx.x * TE0;
    {
        const long e = e0 + tid;
        float wf[H], bf[H];
        #pragma unroll
        for (int h = 0; h < H; ++h) { wf[h] = Wfvb[h]; bf[h] = bfvb[h]; }
        float t1[H];
        #pragma unroll
        for (int h = 0; h < H; ++h) t1[h] = 0.f;
        for (int n = 0; n < N1; ++n) {
            const float dv = d[(long)n * E_DIM + e];
            #pragma unroll
            for (int h = 0; h < H; ++h) t1[h] += fmaxf(fmaf(dv, wf[h], bf[h]), 0.f);
        }
        #pragma unroll
        for (int h = 0; h < H; ++h) t1[h] *= (1.f / N1);
        float vb[H];
        #pragma unroll
        for (int h = 0; h < H; ++h) vb[h] = bgvb[h];
        #pragma unroll
        for (int k = 0; k < H; ++k) {
            const float t = t1[k];
            #pragma unroll
            for (int h = 0; h < H; ++h) vb[h] = fmaf(t, Wgvb[k * H + h], vb[h]);
        }
        #pragma unroll
        for (int h = 0; h < H; ++h) vb[h] = fmaxf(vb[h], 0.f);
        float vw[H];
        #pragma unroll
        for (int h = 0; h < H; ++h) vw[h] = bfu[h];
        #pragma unroll
        for (int k = 0; k < H; ++k) {
            const float t = vb[k];
            #pragma unroll
            for (int h = 0; h < H; ++h) vw[h] = fmaf(t, Wfu[k * H + h], vw[h]);
        }
        #pragma unroll
        for (int h = 0; h < H; ++h) vw_l[tid][h] = vw[h];
    }
    __syncthreads();
    if (tid < N1 * 4) {
        const int n = tid >> 2, hg = tid & 3;
        float wud[8];
        #pragma unroll
        for (int j = 0; j < 8; ++j) wud[j] = Wfu[H * H + hg * 8 + j];
        float acc[8];
        #pragma unroll
        for (int j = 0; j < 8; ++j) acc[j] = 0.f;
        const float* drow = d + (long)n * E_DIM + e0;
        for (int et = 0; et < TE0; et += 4) {
            const float4 d4 = *reinterpret_cast<const float4*>(drow + et);
            const float dv[4] = {d4.x, d4.y, d4.z, d4.w};
            #pragma unroll
            for (int q = 0; q < 4; ++q) {
                #pragma unroll
                for (int j = 0; j < 8; ++j)
                    acc[j] += fmaxf(fmaf(dv[q], wud[j], vw_l[et + q][hg * 8 + j]), 0.f);
            }
        }
        float* ap = alphaAcc + n * H + hg * 8;
        #pragma unroll
        for (int j = 0; j < 8; ++j) atomicAdd(&ap[j], acc[j]);
    }
}

__global__ __launch_bounds__(256) void kC0(
    const float* __restrict__ d, const float* __restrict__ d2,
    const float* __restrict__ uwb,
    const float* __restrict__ Wfvc,
    const float* __restrict__ Wgvc, const float* __restrict__ bgvc,
    const float* __restrict__ Wfz,  const float* __restrict__ bfz,
    float* __restrict__ zAcc)
{
    __shared__ float vz_l[TE0][H + 1];
    const int tid = threadIdx.x;
    const long e0 = (long)blockIdx.x * TE0;
    {
        const long e = e0 + tid;
        float wvd[H];
        #pragma unroll
        for (int h = 0; h < H; ++h) wvd[h] = Wfvc[H * H + h];
        float m[H];
        #pragma unroll
        for (int h = 0; h < H; ++h) m[h] = 0.f;
        for (int n = 0; n < N1; ++n) {
            const float dv = d[(long)n * E_DIM + e];
            const float* ur = uwb + n * H;
            #pragma unroll
            for (int h = 0; h < H; ++h) m[h] += fmaxf(fmaf(dv, wvd[h], ur[h]), 0.f);
        }
        #pragma unroll
        for (int h = 0; h < H; ++h) m[h] *= (1.f / N1);
        float v[H];
        #pragma unroll
        for (int h = 0; h < H; ++h) v[h] = bgvc[h];
        #pragma unroll
        for (int k = 0; k < H; ++k) {
            const float t = m[k];
            #pragma unroll
            for (int h = 0; h < H; ++h) v[h] = fmaf(t, Wgvc[k * H + h], v[h]);
        }
        #pragma unroll
        for (int h = 0; h < H; ++h) v[h] = fmaxf(v[h], 0.f);
        float vz[H];
        #pragma unroll
        for (int h = 0; h < H; ++h) vz[h] = bfz[h];
        #pragma unroll
        for (int k = 0; k < H; ++k) {
            const float t = v[k];
            #pragma unroll
            for (int h = 0; h < H; ++h) vz[h] = fmaf(t, Wfz[k * H + h], vz[h]);
        }
        #pragma unroll
        for (int h = 0; h < H; ++h) vz_l[tid][h] = vz[h];
    }
    __syncthreads();
    if (tid < N1 * 4) {
        const int n2 = tid >> 2, hg = tid & 3;
        float wzd[8];
        #pragma unroll
        for (int j = 0; j < 8; ++j) wzd[j] = Wfz[H * H + hg * 8 + j];
        float acc[8];
        #pragma unroll
        for (int j = 0; j < 8; ++j) acc[j] = 0.f;
        const float* drow = d2 + (long)n2 * E_DIM + e0;
        for (int et = 0; et < TE0; et += 4) {
            const float4 d4 = *reinterpret_cast<const float4*>(drow + et);
            const float dv[4] = {d4.x, d4.y, d4.z, d4.w};
            #pragma unroll
            for (int q = 0; q < 4; ++q) {
                #pragma unroll
                for (int j = 0; j < 8; ++j)
                    acc[j] += fmaxf(fmaf(dv[q], wzd[j], vz_l[et + q][hg * 8 + j]), 0.f);
            }
        }
        float* zp = zAcc + n2 * H + hg * 8;
        #pragma unroll
        for (int j = 0; j < 8; ++j) atomicAdd(&zp[j], acc[j]);
    }
}

extern "C" void kernel_launch(void* const* d_in, const int* in_sizes, int n_in,
                              void* d_out, int out_size, void* d_ws, size_t ws_size,
                              hipStream_t stream)
{
    const float* sup  = (const float*)d_in[0];
    const int*   lab  = (const int*)d_in[1];
    const float* qry  = (const float*)d_in[2];
    const float* Wfvb = (const float*)d_in[3];
    const float* bfvb = (const float*)d_in[4];
    const float* Wgvb = (const float*)d_in[5];
    const float* bgvb = (const float*)d_in[6];
    const float* Wfu  = (const float*)d_in[7];
    const float* bfu  = (const float*)d_in[8];
    const float* Wgu  = (const float*)d_in[9];
    const float* bgu  = (const float*)d_in[10];
    const float* Wfvc = (const float*)d_in[11];
    const float* bfvc = (const float*)d_in[12];
    const float* Wgvc = (const float*)d_in[13];
    const float* bgvc = (const float*)d_in[14];
    const float* Wfz  = (const float*)d_in[15];
    const float* bfz  = (const float*)d_in[16];
    const float* Wgz  = (const float*)d_in[17];
    const float* bgz  = (const float*)d_in[18];
    float* out = (float*)d_out;

    float* alphaAcc = (float*)d_ws;
    float* zAcc     = alphaAcc + PSZ;
    float* uwb      = zAcc + PSZ;
    float* part     = uwb + PSZ;                     // [NBP][PSZ]
    float* vT       = part + (size_t)NBP * PSZ;      // [H][E_DIM], shared vwT/vzT

    const size_t needMain =
        (3 * (size_t)PSZ + (size_t)NBP * PSZ + (size_t)E_DIM * H) * sizeof(float);

    if (ws_size >= needMain) {
        kP1<<<NB1, 256, 0, stream>>>(sup, Wfvb, bfvb, Wgvb, bgvb, Wfu, bfu, vT);
        kP2<<<NBP, 512, 0, stream>>>(sup, vT, Wfu, part);
        kR<<<PSZ / 16, 256, 0, stream>>>(part, alphaAcc);
        kB<<<1, 1024, 0, stream>>>(alphaAcc, lab, Wfvb, bfvb, Wgvb, bgvb, Wfu, bfu,
                                   Wgu, bgu, Wfvc, bfvc, 1.f / N1, uwb);
        kP4<<<NB1, 256, 0, stream>>>(sup, uwb, Wfvc, Wgvc, bgvc, Wfz, bfz, vT);
        kP2<<<NBP, 512, 0, stream>>>(qry, vT, Wfz, part);
        kR<<<PSZ / 16, 256, 0, stream>>>(part, zAcc);
        kD<<<1, 1024, 0, stream>>>(zAcc, Wgz, bgz, out);
    } else {
        (void)hipMemsetAsync(alphaAcc, 0, 2 * PSZ * sizeof(float), stream);
        kA0<<<NB0, 256, 0, stream>>>(sup, Wfvb, bfvb, Wgvb, bgvb, Wfu, bfu, alphaAcc);
        kB<<<1, 1024, 0, stream>>>(alphaAcc, lab, Wfvb, bfvb, Wgvb, bgvb, Wfu, bfu,
                                   Wgu, bgu, Wfvc, bfvc, 1.f, uwb);
        kC0<<<NB0, 256, 0, stream>>>(sup, qry, uwb, Wfvc, Wgvc, bgvc, Wfz, bfz, zAcc);
        kD<<<1, 1024, 0, stream>>>(zAcc, Wgz, bgz, out);
    }
}